// Round 9
// baseline (462.308 us; speedup 1.0000x reference)
//
#include <hip/hip_runtime.h>

// LocalAutoCorr2D: out[b,iy,ix,c,dy,dx] =
//   sum_{u,v in [0,8)} x[b,c,4iy+u,4ix+v] * x[b,c,4iy+dy+u-4,4ix+dx+v-4]  (zero-padded)
//
// B=4 C=128 H=W=128, kh=kw=8, sh=sw=4, nh=nw=31.
// Block: 256 threads = 4 ch x 8 px x 4 py x 2 dy-halves; thread owns acc[4][8]
// (dy = half*4+d). Base rows re-derived via 4-slot rolling register cache (ks):
// half 0 sweeps rows DESCENDING, half 1 ASCENDING -> zero base-row LDS reads.
// Direct register->global stores (thread's 32 outputs = contiguous 128B chunk).
// 19.8KB LDS. launch_bounds(256,5): empirically the 2nd arg CAPS resident
// waves/EU on this stack (r1/r4/r5/r6 ladder) -> declare 5 to actually get
// ~5 blocks/CU; RA budget 512/5=102 >= ~92-reg live set, so no spills expected.

#define Cn 128
#define Hn 128
#define Wn 128
#define NH 31
#define NW 31
#define CB 4             // channels per block
#define PXT 8            // x positions per block
#define PYT 4            // y positions per block
#define TROWS 27         // (PYT-1)*4 + 15
#define RST 44           // floats per region row (43 used)
#define CSTF4 310        // float4 per channel (297 used; 310%8=6 -> 2-way max aliasing)
#define F4C (TROWS*11)   // 297 float4 staged per channel

__global__ __launch_bounds__(256, 5)
void lac_kernel(const float* __restrict__ x, float* __restrict__ out) {
    __shared__ float sm[CB * CSTF4 * 4];   // 19,840 B

    // XCD-chunked swizzle: 4096 blocks, 512 consecutive logical ids per XCD.
    const int bid = blockIdx.x;
    const int lg = ((bid & 7) << 9) | (bid >> 3);
    const int tx = lg & 3;           // x tile 0..3
    const int ty = (lg >> 2) & 7;    // y tile 0..7
    const int ct = (lg >> 5) & 31;   // channel tile 0..31
    const int b  = lg >> 10;         // batch 0..3
    const int c0 = ct * CB;
    const int gy0 = ty * (PYT * 4) - 4;
    const int gx0 = tx * (PXT * 4) - 4;
    const int tid = threadIdx.x;

    // ---- stage region: CB channels x 27 rows x 44 cols (float4) ----
    const bool interior = (gy0 >= 0) & (gy0 + TROWS <= Hn) & (gx0 >= 0) & (gx0 + RST <= Wn);
    if (interior) {
        // wave-uniform fast path: no boundary predicates
        for (int i = tid; i < CB * F4C; i += 256) {
            const int c   = i / F4C;
            const int rem = i - c * F4C;
            const int r   = rem / 11;
            const int q   = rem - r * 11;
            const float* src = x + (((size_t)(b * Cn + c0 + c) * Hn + gy0 + r) * Wn + gx0 + q * 4);
            reinterpret_cast<float4*>(sm)[c * CSTF4 + r * 11 + q] =
                *reinterpret_cast<const float4*>(src);
        }
    } else {
        for (int i = tid; i < CB * F4C; i += 256) {
            const int c   = i / F4C;
            const int rem = i - c * F4C;
            const int r   = rem / 11;
            const int q   = rem - r * 11;
            const int y   = gy0 + r;
            const int xc  = gx0 + q * 4;
            const float* src = x + (((size_t)(b * Cn + c0 + c) * Hn + y) * Wn + xc);
            float4 v;
            if (y >= 0 && y < Hn && xc >= 0 && xc + 3 < Wn) {
                v = *reinterpret_cast<const float4*>(src);
            } else if (y >= 0 && y < Hn) {
                v.x = (xc + 0 >= 0 && xc + 0 < Wn) ? src[0] : 0.0f;
                v.y = (xc + 1 >= 0 && xc + 1 < Wn) ? src[1] : 0.0f;
                v.z = (xc + 2 >= 0 && xc + 2 < Wn) ? src[2] : 0.0f;
                v.w = (xc + 3 >= 0 && xc + 3 < Wn) ? src[3] : 0.0f;
            } else {
                v = make_float4(0.0f, 0.0f, 0.0f, 0.0f);
            }
            reinterpret_cast<float4*>(sm)[c * CSTF4 + r * 11 + q] = v;
        }
    }
    __syncthreads();

    // ---- compute: thread = (cs, px, py, half); acc[d][dx], dy = half*4+d ----
    const int cs   = tid & 3;
    const int px   = (tid >> 2) & 7;
    const int py   = (tid >> 5) & 3;
    const int half = tid >> 7;                 // wave-uniform
    const float* rg = &sm[cs * (CSTF4 * 4) + (py * 4) * RST + px * 4];

    float acc[4][8];
#pragma unroll
    for (int i = 0; i < 4; ++i)
#pragma unroll
        for (int j = 0; j < 8; ++j) acc[i][j] = 0.0f;

    float ks[4][8];   // rolling cache: ks[row&3][v] = X[row][v+4] (cols 4..11)

#define LOAD_RW(R)                                                              \
    float rw[16];                                                               \
    {                                                                           \
        float4 q0 = *reinterpret_cast<const float4*>(&rg[(R) * RST + 0]);       \
        float4 q1 = *reinterpret_cast<const float4*>(&rg[(R) * RST + 4]);       \
        float4 q2 = *reinterpret_cast<const float4*>(&rg[(R) * RST + 8]);       \
        float4 q3 = *reinterpret_cast<const float4*>(&rg[(R) * RST + 12]);      \
        rw[0]=q0.x; rw[1]=q0.y; rw[2]=q0.z; rw[3]=q0.w;                         \
        rw[4]=q1.x; rw[5]=q1.y; rw[6]=q1.z; rw[7]=q1.w;                         \
        rw[8]=q2.x; rw[9]=q2.y; rw[10]=q2.z; rw[11]=q2.w;                       \
        rw[12]=q3.x; rw[13]=q3.y; rw[14]=q3.z; rw[15]=q3.w;                     \
    }

    if (half == 0) {
        // dy = d. Descending sweep R=11..0. At row R: shifted = rw (row R),
        // base row cached in ks[(R-d)&3] (saved 4-d iters ago).
#pragma unroll
        for (int ii = 0; ii < 12; ++ii) {
            const int R = 11 - ii;
            LOAD_RW(R)
#pragma unroll
            for (int d = 0; d < 4; ++d) {
                if (R >= d && R <= 7 + d) {          // compile-time predicate
#pragma unroll
                    for (int v = 0; v < 8; ++v) {
                        const float bv = ks[(R - d) & 3][v];
#pragma unroll
                        for (int dx = 0; dx < 8; ++dx)
                            acc[d][dx] = fmaf(bv, rw[dx + v], acc[d][dx]);
                    }
                }
            }
#pragma unroll
            for (int v = 0; v < 8; ++v) ks[R & 3][v] = rw[4 + v];
        }
    } else {
        // dy = 4+d. Ascending sweep R=4..14. d=0 -> current rw[4..11],
        // d>=1 -> ks[(R-d)&3] (saved d iters ago).
#pragma unroll
        for (int ii = 0; ii < 11; ++ii) {
            const int R = 4 + ii;
            LOAD_RW(R)
#pragma unroll
            for (int d = 0; d < 4; ++d) {
                if (R >= 4 + d && R <= 11 + d) {     // compile-time predicate
#pragma unroll
                    for (int v = 0; v < 8; ++v) {
                        const float bv = (d == 0) ? rw[4 + v] : ks[(R - d) & 3][v];
#pragma unroll
                        for (int dx = 0; dx < 8; ++dx)
                            acc[d][dx] = fmaf(bv, rw[dx + v], acc[d][dx]);
                    }
                }
            }
#pragma unroll
            for (int v = 0; v < 8; ++v) ks[R & 3][v] = rw[4 + v];
        }
    }
#undef LOAD_RW

    // ---- direct store: thread's 32 outputs = one contiguous 128B chunk ----
    // out index = ((b,iy,ix)*Cn + c0+cs)*64 + (half*4+d)*8 + dx
    const int iy = ty * PYT + py;
    const int ix = tx * PXT + px;
    if (iy < NH && ix < NW) {
        float* o = out + ((((size_t)b * NH + iy) * NW + ix) * Cn + (c0 + cs)) * 64
                       + half * 32;
#pragma unroll
        for (int d = 0; d < 4; ++d) {
            *reinterpret_cast<float4*>(o + d * 8 + 0) =
                make_float4(acc[d][0], acc[d][1], acc[d][2], acc[d][3]);
            *reinterpret_cast<float4*>(o + d * 8 + 4) =
                make_float4(acc[d][4], acc[d][5], acc[d][6], acc[d][7]);
        }
    }
}

extern "C" void kernel_launch(void* const* d_in, const int* in_sizes, int n_in,
                              void* d_out, int out_size, void* d_ws, size_t ws_size,
                              hipStream_t stream) {
    const float* x = (const float*)d_in[0];
    float* out = (float*)d_out;
    // grid = b(4) * ct(32) * ty(8) * tx(4) = 4096 blocks
    lac_kernel<<<dim3(4096), dim3(256), 0, stream>>>(x, out);
}

// Round 10
// 90.249 us; speedup vs baseline: 5.1226x; 5.1226x over previous
//
#include <hip/hip_runtime.h>

// LocalAutoCorr2D: out[b,iy,ix,c,dy,dx] =
//   sum_{u,v in [0,8)} x[b,c,4iy+u,4ix+v] * x[b,c,4iy+dy+u-4,4ix+dx+v-4]  (zero-padded)
//
// B=4 C=128 H=W=128, kh=kw=8, sh=sw=4, nh=nw=31.
// Block: 256 threads = 4 ch x 8 px x 4 py x 2 dy-halves; thread owns acc[4][8]
// (dy = half*4+d). Base rows via 4-slot rolling register cache (ks); half 0
// sweeps DESCENDING, half 1 ASCENDING -> zero base-row LDS reads.
// NEW (r10): one-row rw lookahead — next row's 4x ds_read_b128 issued BEFORE
// the current row's FMA burst, hiding LDS latency under ~340 cyc of FMAs.
// Live set ~108 regs -> fits the (256,2) 128-reg allocation, no spills.
// Direct register->global stores. 19.8KB LDS. XCD-chunked swizzle.

#define Cn 128
#define Hn 128
#define Wn 128
#define NH 31
#define NW 31
#define CB 4             // channels per block
#define PXT 8            // x positions per block
#define PYT 4            // y positions per block
#define TROWS 27         // (PYT-1)*4 + 15
#define RST 44           // floats per region row (43 used)
#define CSTF4 310        // float4 per channel (297 used)
#define F4C (TROWS*11)   // 297 float4 staged per channel

__global__ __launch_bounds__(256, 2)
void lac_kernel(const float* __restrict__ x, float* __restrict__ out) {
    __shared__ float sm[CB * CSTF4 * 4];   // 19,840 B

    // XCD-chunked swizzle: 4096 blocks, 512 consecutive logical ids per XCD.
    const int bid = blockIdx.x;
    const int lg = ((bid & 7) << 9) | (bid >> 3);
    const int tx = lg & 3;           // x tile 0..3
    const int ty = (lg >> 2) & 7;    // y tile 0..7
    const int ct = (lg >> 5) & 31;   // channel tile 0..31
    const int b  = lg >> 10;         // batch 0..3
    const int c0 = ct * CB;
    const int gy0 = ty * (PYT * 4) - 4;
    const int gx0 = tx * (PXT * 4) - 4;
    const int tid = threadIdx.x;

    // ---- stage region: CB channels x 27 rows x 44 cols (float4) ----
    const bool interior = (gy0 >= 0) & (gy0 + TROWS <= Hn) & (gx0 >= 0) & (gx0 + RST <= Wn);
    if (interior) {
        for (int i = tid; i < CB * F4C; i += 256) {
            const int c   = i / F4C;
            const int rem = i - c * F4C;
            const int r   = rem / 11;
            const int q   = rem - r * 11;
            const float* src = x + (((size_t)(b * Cn + c0 + c) * Hn + gy0 + r) * Wn + gx0 + q * 4);
            reinterpret_cast<float4*>(sm)[c * CSTF4 + r * 11 + q] =
                *reinterpret_cast<const float4*>(src);
        }
    } else {
        for (int i = tid; i < CB * F4C; i += 256) {
            const int c   = i / F4C;
            const int rem = i - c * F4C;
            const int r   = rem / 11;
            const int q   = rem - r * 11;
            const int y   = gy0 + r;
            const int xc  = gx0 + q * 4;
            const float* src = x + (((size_t)(b * Cn + c0 + c) * Hn + y) * Wn + xc);
            float4 v;
            if (y >= 0 && y < Hn && xc >= 0 && xc + 3 < Wn) {
                v = *reinterpret_cast<const float4*>(src);
            } else if (y >= 0 && y < Hn) {
                v.x = (xc + 0 >= 0 && xc + 0 < Wn) ? src[0] : 0.0f;
                v.y = (xc + 1 >= 0 && xc + 1 < Wn) ? src[1] : 0.0f;
                v.z = (xc + 2 >= 0 && xc + 2 < Wn) ? src[2] : 0.0f;
                v.w = (xc + 3 >= 0 && xc + 3 < Wn) ? src[3] : 0.0f;
            } else {
                v = make_float4(0.0f, 0.0f, 0.0f, 0.0f);
            }
            reinterpret_cast<float4*>(sm)[c * CSTF4 + r * 11 + q] = v;
        }
    }
    __syncthreads();

    // ---- compute: thread = (cs, px, py, half); acc[d][dx], dy = half*4+d ----
    const int cs   = tid & 3;
    const int px   = (tid >> 2) & 7;
    const int py   = (tid >> 5) & 3;
    const int half = tid >> 7;                 // wave-uniform
    const float* rg = &sm[cs * (CSTF4 * 4) + (py * 4) * RST + px * 4];

    float acc[4][8];
#pragma unroll
    for (int i = 0; i < 4; ++i)
#pragma unroll
        for (int j = 0; j < 8; ++j) acc[i][j] = 0.0f;

    float ks[4][8];   // rolling cache: ks[row&3][v] = X[row][v+4] (cols 4..11)

#define LOAD_RW(dst, R)                                                         \
    {                                                                           \
        float4 q0 = *reinterpret_cast<const float4*>(&rg[(R) * RST + 0]);       \
        float4 q1 = *reinterpret_cast<const float4*>(&rg[(R) * RST + 4]);       \
        float4 q2 = *reinterpret_cast<const float4*>(&rg[(R) * RST + 8]);       \
        float4 q3 = *reinterpret_cast<const float4*>(&rg[(R) * RST + 12]);      \
        dst[0]=q0.x; dst[1]=q0.y; dst[2]=q0.z; dst[3]=q0.w;                     \
        dst[4]=q1.x; dst[5]=q1.y; dst[6]=q1.z; dst[7]=q1.w;                     \
        dst[8]=q2.x; dst[9]=q2.y; dst[10]=q2.z; dst[11]=q2.w;                   \
        dst[12]=q3.x; dst[13]=q3.y; dst[14]=q3.z; dst[15]=q3.w;                 \
    }

    if (half == 0) {
        // dy = d. Descending sweep R=11..0; base row cached in ks[(R-d)&3].
        float rw[16];
        LOAD_RW(rw, 11)
#pragma unroll
        for (int ii = 0; ii < 12; ++ii) {
            const int R = 11 - ii;
            float rwN[16];
            if (ii < 11) LOAD_RW(rwN, R - 1)      // prefetch next row
#pragma unroll
            for (int d = 0; d < 4; ++d) {
                if (R >= d && R <= 7 + d) {       // compile-time predicate
#pragma unroll
                    for (int v = 0; v < 8; ++v) {
                        const float bv = ks[(R - d) & 3][v];
#pragma unroll
                        for (int dx = 0; dx < 8; ++dx)
                            acc[d][dx] = fmaf(bv, rw[dx + v], acc[d][dx]);
                    }
                }
            }
#pragma unroll
            for (int v = 0; v < 8; ++v) ks[R & 3][v] = rw[4 + v];
            if (ii < 11) {
#pragma unroll
                for (int v = 0; v < 16; ++v) rw[v] = rwN[v];   // SSA-renamed away
            }
        }
    } else {
        // dy = 4+d. Ascending sweep R=4..14; d=0 -> current row, d>=1 -> ks.
        float rw[16];
        LOAD_RW(rw, 4)
#pragma unroll
        for (int ii = 0; ii < 11; ++ii) {
            const int R = 4 + ii;
            float rwN[16];
            if (ii < 10) LOAD_RW(rwN, R + 1)      // prefetch next row
#pragma unroll
            for (int d = 0; d < 4; ++d) {
                if (R >= 4 + d && R <= 11 + d) {  // compile-time predicate
#pragma unroll
                    for (int v = 0; v < 8; ++v) {
                        const float bv = (d == 0) ? rw[4 + v] : ks[(R - d) & 3][v];
#pragma unroll
                        for (int dx = 0; dx < 8; ++dx)
                            acc[d][dx] = fmaf(bv, rw[dx + v], acc[d][dx]);
                    }
                }
            }
#pragma unroll
            for (int v = 0; v < 8; ++v) ks[R & 3][v] = rw[4 + v];
            if (ii < 10) {
#pragma unroll
                for (int v = 0; v < 16; ++v) rw[v] = rwN[v];   // SSA-renamed away
            }
        }
    }
#undef LOAD_RW

    // ---- direct store: thread's 32 outputs = one contiguous 128B chunk ----
    const int iy = ty * PYT + py;
    const int ix = tx * PXT + px;
    if (iy < NH && ix < NW) {
        float* o = out + ((((size_t)b * NH + iy) * NW + ix) * Cn + (c0 + cs)) * 64
                       + half * 32;
#pragma unroll
        for (int d = 0; d < 4; ++d) {
            *reinterpret_cast<float4*>(o + d * 8 + 0) =
                make_float4(acc[d][0], acc[d][1], acc[d][2], acc[d][3]);
            *reinterpret_cast<float4*>(o + d * 8 + 4) =
                make_float4(acc[d][4], acc[d][5], acc[d][6], acc[d][7]);
        }
    }
}

extern "C" void kernel_launch(void* const* d_in, const int* in_sizes, int n_in,
                              void* d_out, int out_size, void* d_ws, size_t ws_size,
                              hipStream_t stream) {
    const float* x = (const float*)d_in[0];
    float* out = (float*)d_out;
    // grid = b(4) * ct(32) * ty(8) * tx(4) = 4096 blocks
    lac_kernel<<<dim3(4096), dim3(256), 0, stream>>>(x, out);
}

// Round 11
// 87.709 us; speedup vs baseline: 5.2709x; 1.0290x over previous
//
#include <hip/hip_runtime.h>

// LocalAutoCorr2D: out[b,iy,ix,c,dy,dx] =
//   sum_{u,v in [0,8)} x[b,c,4iy+u,4ix+v] * x[b,c,4iy+dy+u-4,4ix+dx+v-4]  (zero-padded)
//
// B=4 C=128 H=W=128, kh=kw=8, sh=sw=4, nh=nw=31.
// Block: 256 threads = 4 ch x 8 px x 4 py x 2 dy-halves; thread owns acc[4][8]
// (dy = half*4+d). Base rows via 3-slot rolling register cache (ks); the lag-4
// case (half0 d=0) reads its base row directly from LDS in two 4-col chunks.
// Live set ~80 regs -> fits the empirical 84-reg allocation at
// __launch_bounds__(256,3) -> 3 blocks/CU (the 2nd arg caps residency:
// r1/r4/r5/r6 ladder). Direct register->global stores. 19.8KB LDS.
// XCD-chunked swizzle. Alloc law on this stack: alloc = 256/N.

#define Cn 128
#define Hn 128
#define Wn 128
#define NH 31
#define NW 31
#define CB 4             // channels per block
#define PXT 8            // x positions per block
#define PYT 4            // y positions per block
#define TROWS 27         // (PYT-1)*4 + 15
#define RST 44           // floats per region row (43 used)
#define CSTF4 310        // float4 per channel (297 used)
#define F4C (TROWS*11)   // 297 float4 staged per channel

__global__ __launch_bounds__(256, 3)
void lac_kernel(const float* __restrict__ x, float* __restrict__ out) {
    __shared__ float sm[CB * CSTF4 * 4];   // 19,840 B

    // XCD-chunked swizzle: 4096 blocks, 512 consecutive logical ids per XCD.
    const int bid = blockIdx.x;
    const int lg = ((bid & 7) << 9) | (bid >> 3);
    const int tx = lg & 3;           // x tile 0..3
    const int ty = (lg >> 2) & 7;    // y tile 0..7
    const int ct = (lg >> 5) & 31;   // channel tile 0..31
    const int b  = lg >> 10;         // batch 0..3
    const int c0 = ct * CB;
    const int gy0 = ty * (PYT * 4) - 4;
    const int gx0 = tx * (PXT * 4) - 4;
    const int tid = threadIdx.x;

    // ---- stage region: CB channels x 27 rows x 44 cols (float4) ----
    const bool interior = (gy0 >= 0) & (gy0 + TROWS <= Hn) & (gx0 >= 0) & (gx0 + RST <= Wn);
    if (interior) {
        for (int i = tid; i < CB * F4C; i += 256) {
            const int c   = i / F4C;
            const int rem = i - c * F4C;
            const int r   = rem / 11;
            const int q   = rem - r * 11;
            const float* src = x + (((size_t)(b * Cn + c0 + c) * Hn + gy0 + r) * Wn + gx0 + q * 4);
            reinterpret_cast<float4*>(sm)[c * CSTF4 + r * 11 + q] =
                *reinterpret_cast<const float4*>(src);
        }
    } else {
        for (int i = tid; i < CB * F4C; i += 256) {
            const int c   = i / F4C;
            const int rem = i - c * F4C;
            const int r   = rem / 11;
            const int q   = rem - r * 11;
            const int y   = gy0 + r;
            const int xc  = gx0 + q * 4;
            const float* src = x + (((size_t)(b * Cn + c0 + c) * Hn + y) * Wn + xc);
            float4 v;
            if (y >= 0 && y < Hn && xc >= 0 && xc + 3 < Wn) {
                v = *reinterpret_cast<const float4*>(src);
            } else if (y >= 0 && y < Hn) {
                v.x = (xc + 0 >= 0 && xc + 0 < Wn) ? src[0] : 0.0f;
                v.y = (xc + 1 >= 0 && xc + 1 < Wn) ? src[1] : 0.0f;
                v.z = (xc + 2 >= 0 && xc + 2 < Wn) ? src[2] : 0.0f;
                v.w = (xc + 3 >= 0 && xc + 3 < Wn) ? src[3] : 0.0f;
            } else {
                v = make_float4(0.0f, 0.0f, 0.0f, 0.0f);
            }
            reinterpret_cast<float4*>(sm)[c * CSTF4 + r * 11 + q] = v;
        }
    }
    __syncthreads();

    // ---- compute: thread = (cs, px, py, half); acc[d][dx], dy = half*4+d ----
    const int cs   = tid & 3;
    const int px   = (tid >> 2) & 7;
    const int py   = (tid >> 5) & 3;
    const int half = tid >> 7;                 // wave-uniform
    const float* rg = &sm[cs * (CSTF4 * 4) + (py * 4) * RST + px * 4];

    float acc[4][8];
#pragma unroll
    for (int i = 0; i < 4; ++i)
#pragma unroll
        for (int j = 0; j < 8; ++j) acc[i][j] = 0.0f;

    float ks[3][8];   // rolling cache (depth 3): ks[row%3][v] = X[row][v+4]

#define LOAD_RW(dst, R)                                                         \
    {                                                                           \
        float4 q0 = *reinterpret_cast<const float4*>(&rg[(R) * RST + 0]);       \
        float4 q1 = *reinterpret_cast<const float4*>(&rg[(R) * RST + 4]);       \
        float4 q2 = *reinterpret_cast<const float4*>(&rg[(R) * RST + 8]);       \
        float4 q3 = *reinterpret_cast<const float4*>(&rg[(R) * RST + 12]);      \
        dst[0]=q0.x; dst[1]=q0.y; dst[2]=q0.z; dst[3]=q0.w;                     \
        dst[4]=q1.x; dst[5]=q1.y; dst[6]=q1.z; dst[7]=q1.w;                     \
        dst[8]=q2.x; dst[9]=q2.y; dst[10]=q2.z; dst[11]=q2.w;                   \
        dst[12]=q3.x; dst[13]=q3.y; dst[14]=q3.z; dst[15]=q3.w;                 \
    }

    if (half == 0) {
        // dy = d. Descending sweep R=11..0. Base row = R+4-d.
        // d=1..3: lag 1..3 -> ks (stored at steps R+1..R+3, which run FIRST).
        // d=0: lag 4 -> direct LDS read of row R+4 center cols (two 4-chunks).
        float rw[16];
#pragma unroll
        for (int ii = 0; ii < 12; ++ii) {
            const int R = 11 - ii;
            LOAD_RW(rw, R)
#pragma unroll
            for (int d = 1; d < 4; ++d) {
                if (R >= d && R <= 7 + d) {       // compile-time predicate
#pragma unroll
                    for (int v = 0; v < 8; ++v) {
                        const float bv = ks[(R + 4 - d) % 3][v];
#pragma unroll
                        for (int dx = 0; dx < 8; ++dx)
                            acc[d][dx] = fmaf(bv, rw[dx + v], acc[d][dx]);
                    }
                }
            }
            if (R <= 7) {                         // d = 0, compile-time
                {
                    float4 b0 = *reinterpret_cast<const float4*>(&rg[(R + 4) * RST + 4]);
                    const float bb0[4] = {b0.x, b0.y, b0.z, b0.w};
#pragma unroll
                    for (int v = 0; v < 4; ++v)
#pragma unroll
                        for (int dx = 0; dx < 8; ++dx)
                            acc[0][dx] = fmaf(bb0[v], rw[dx + v], acc[0][dx]);
                }
                {
                    float4 b1 = *reinterpret_cast<const float4*>(&rg[(R + 4) * RST + 8]);
                    const float bb1[4] = {b1.x, b1.y, b1.z, b1.w};
#pragma unroll
                    for (int v = 0; v < 4; ++v)
#pragma unroll
                        for (int dx = 0; dx < 8; ++dx)
                            acc[0][dx] = fmaf(bb1[v], rw[dx + 4 + v], acc[0][dx]);
                }
            }
#pragma unroll
            for (int v = 0; v < 8; ++v) ks[R % 3][v] = rw[4 + v];
        }
    } else {
        // dy = 4+d. Ascending sweep R=4..14. Base row = R-d.
        // d=0 -> current rw[4..11]; d=1..3 -> ks (lag 1..3).
        float rw[16];
#pragma unroll
        for (int ii = 0; ii < 11; ++ii) {
            const int R = 4 + ii;
            LOAD_RW(rw, R)
            if (R <= 11) {                        // d = 0, compile-time
#pragma unroll
                for (int v = 0; v < 8; ++v) {
                    const float bv = rw[4 + v];
#pragma unroll
                    for (int dx = 0; dx < 8; ++dx)
                        acc[0][dx] = fmaf(bv, rw[dx + v], acc[0][dx]);
                }
            }
#pragma unroll
            for (int d = 1; d < 4; ++d) {
                if (R >= 4 + d && R <= 11 + d) {  // compile-time predicate
#pragma unroll
                    for (int v = 0; v < 8; ++v) {
                        const float bv = ks[(R - d) % 3][v];
#pragma unroll
                        for (int dx = 0; dx < 8; ++dx)
                            acc[d][dx] = fmaf(bv, rw[dx + v], acc[d][dx]);
                    }
                }
            }
#pragma unroll
            for (int v = 0; v < 8; ++v) ks[R % 3][v] = rw[4 + v];
        }
    }
#undef LOAD_RW

    // ---- direct store: thread's 32 outputs = one contiguous 128B chunk ----
    const int iy = ty * PYT + py;
    const int ix = tx * PXT + px;
    if (iy < NH && ix < NW) {
        float* o = out + ((((size_t)b * NH + iy) * NW + ix) * Cn + (c0 + cs)) * 64
                       + half * 32;
#pragma unroll
        for (int d = 0; d < 4; ++d) {
            *reinterpret_cast<float4*>(o + d * 8 + 0) =
                make_float4(acc[d][0], acc[d][1], acc[d][2], acc[d][3]);
            *reinterpret_cast<float4*>(o + d * 8 + 4) =
                make_float4(acc[d][4], acc[d][5], acc[d][6], acc[d][7]);
        }
    }
}

extern "C" void kernel_launch(void* const* d_in, const int* in_sizes, int n_in,
                              void* d_out, int out_size, void* d_ws, size_t ws_size,
                              hipStream_t stream) {
    const float* x = (const float*)d_in[0];
    float* out = (float*)d_out;
    // grid = b(4) * ct(32) * ty(8) * tx(4) = 4096 blocks
    lac_kernel<<<dim3(4096), dim3(256), 0, stream>>>(x, out);
}